// Round 11
// baseline (386.323 us; speedup 1.0000x reference)
//
#include <hip/hip_runtime.h>
#include <hip/hip_bf16.h>

// ---------- types ----------
typedef unsigned short u16;
typedef unsigned int u32;
typedef float f32x4 __attribute__((ext_vector_type(4)));
typedef _Float16 f16x8 __attribute__((ext_vector_type(8)));
typedef u32 u32x4 __attribute__((ext_vector_type(4)));
typedef u32 u32x2 __attribute__((ext_vector_type(2)));

#define SEQ 2048
#define EDIM 1024

__device__ __forceinline__ u16 f2h(float f) {
  _Float16 h = (_Float16)f;
  return __builtin_bit_cast(u16, h);
}
__device__ __forceinline__ float h2f(u16 u) {
  return (float)__builtin_bit_cast(_Float16, u);
}
__device__ __forceinline__ u32 pk(float a, float b) {
  return (u32)f2h(a) | ((u32)f2h(b) << 16);
}

// ---------- fused fp32 -> fp16 convert for all 4 inputs, 8 elems/thread ----
#define N_X  2097152
#define N_WP 327680
#define N_W1 131072
#define N_W2 131072
__global__ __launch_bounds__(256) void cvt_all(const float* __restrict__ x, u16* __restrict__ xb,
                                               const float* __restrict__ wp, u16* __restrict__ wpb,
                                               const float* __restrict__ w1, u16* __restrict__ w1b,
                                               const float* __restrict__ w2, u16* __restrict__ w2b) {
  int i = blockIdx.x * 256 + threadIdx.x;
  const float* src; u16* dst; int li;
  if (i < N_X) { src = x; dst = xb; li = i; }
  else if (i < N_X + N_WP) { src = wp; dst = wpb; li = i - N_X; }
  else if (i < N_X + N_WP + N_W1) { src = w1; dst = w1b; li = i - N_X - N_WP; }
  else if (i < N_X + N_WP + N_W1 + N_W2) { src = w2; dst = w2b; li = i - N_X - N_WP - N_W1; }
  else return;
  const f32x4* p = (const f32x4*)(src + (size_t)li * 8);
  f32x4 a = p[0], b = p[1];
  u32x4 o = {pk(a[0], a[1]), pk(a[2], a[3]), pk(b[0], b[1]), pk(b[2], b[3])};
  *(u32x4*)(dst + (size_t)li * 8) = o;
}

struct GemmP {
  const u16* A; const u16* B;
  int lda, ldb, K;
  long bsA, bsB, bsC;       // per-blockIdx.z element strides
  int ldc;
  u16* Cb;                  // f16 store
  const float* bias;        // EPI 2,3
  const u16* resid;         // EPI 3 (h, f16, ld 512)
  u16* qk; u16* vT;         // EPI 1 (proj split)
  float scale;              // EPI 1
};

// =======================================================================
// 128x128 tile, BK=64, 4 waves (2x2), 16x16x32 f16 MFMA, COVERED-STAGING
// 2-phase double-buffer (round-8 proven best: proj 100.3us / MfmaUtil 38.2).
// LDS 64KB -> 2 blocks/CU. Used for proj, PV, ff2.
// EPI: 1 = proj split (q*SC | k | vT), 3 = +bias +resid f16 (ff2),
//      4 = plain f16 (PV).
// =======================================================================
template <int EPI>
__global__ __launch_bounds__(256) void gemm_bt(GemmP p) {
  __shared__ __align__(16) char lds[65536];
  const int tid = threadIdx.x;
  const int lane = tid & 63;
  const int wave = tid >> 6;
  const int wm = wave >> 1, wn = wave & 1;
  const int bn0 = blockIdx.x * 128;
  const int bm0 = blockIdx.y * 128;
  const int z = blockIdx.z;

  const u16* gA[4]; const u16* gB[4];
  int ldsA[4], ldsB[4];
  {
    const u16* Ab = p.A + (long)z * p.bsA + (long)bm0 * p.lda;
    const u16* Bb = p.B + (long)z * p.bsB + (long)bn0 * p.ldb;
#pragma unroll
    for (int i = 0; i < 4; ++i) {
      int ch = i * 256 + tid;
      int row = ch >> 3, s = ch & 7;
      int ks = ((s ^ (row & 7)) << 3);  // inverse-swizzled global source
      gA[i] = Ab + (long)row * p.lda + ks;
      gB[i] = Bb + (long)row * p.ldb + ks;
      ldsA[i] = ch * 16;
      ldsB[i] = 16384 + ch * 16;
    }
  }
  auto stage = [&](int buf) {
    char* dst = lds + buf * 32768;
#pragma unroll
    for (int i = 0; i < 4; ++i) {
      __builtin_amdgcn_global_load_lds(
          (const __attribute__((address_space(1))) u32*)gA[i],
          (__attribute__((address_space(3))) u32*)(dst + ldsA[i]), 16, 0, 0);
      gA[i] += 64;
    }
#pragma unroll
    for (int i = 0; i < 4; ++i) {
      __builtin_amdgcn_global_load_lds(
          (const __attribute__((address_space(1))) u32*)gB[i],
          (__attribute__((address_space(3))) u32*)(dst + ldsB[i]), 16, 0, 0);
      gB[i] += 64;
    }
  };

  int ao[2][4], bo[2][4];
#pragma unroll
  for (int h = 0; h < 2; ++h) {
#pragma unroll
    for (int i = 0; i < 4; ++i) {
      int rA = wm * 64 + i * 16 + (lane & 15);
      ao[h][i] = rA * 128 + ((((h << 2) | (lane >> 4)) ^ (rA & 7)) << 4);
      int rB = wn * 64 + i * 16 + (lane & 15);
      bo[h][i] = 16384 + rB * 128 + ((((h << 2) | (lane >> 4)) ^ (rB & 7)) << 4);
    }
  }

  f32x4 acc[4][4] = {};
  stage(0);
  const int nk = p.K >> 6;
  int cur = 0;
  for (int kt = 0; kt < nk; ++kt) {
    __syncthreads();                  // buf[cur] landed; drain covered by prev tile
    if (kt + 1 < nk) stage(cur ^ 1);  // issue next tile FIRST
    const char* base = lds + cur * 32768;
#pragma unroll
    for (int h = 0; h < 2; ++h) {
      f16x8 av[4], bv[4];
#pragma unroll
      for (int i = 0; i < 4; ++i) av[i] = *(const f16x8*)(base + ao[h][i]);
#pragma unroll
      for (int j = 0; j < 4; ++j) bv[j] = *(const f16x8*)(base + bo[h][j]);
#pragma unroll
      for (int i = 0; i < 4; ++i)
#pragma unroll
        for (int j = 0; j < 4; ++j)
          acc[i][j] = __builtin_amdgcn_mfma_f32_16x16x32_f16(av[i], bv[j], acc[i][j], 0, 0, 0);
    }
    cur ^= 1;
  }

  // epilogue: C row = (lane>>4)*4+reg, col = lane&15 (m89 layout)
#pragma unroll
  for (int i = 0; i < 4; ++i) {
#pragma unroll
    for (int j = 0; j < 4; ++j) {
      int mb = bm0 + wm * 64 + i * 16 + ((lane >> 4) << 2);
      int n = bn0 + wn * 64 + j * 16 + (lane & 15);
      if constexpr (EPI == 1) {  // proj split into q*SCALE | k | vT
        int b = mb >> 11, l0 = mb & 2047;
        if (n < EDIM) {
          u16* dst = p.qk + (long)b * 4194304 + (long)l0 * 1024 + n;
#pragma unroll
          for (int r = 0; r < 4; ++r) dst[r * 1024] = f2h(acc[i][j][r] * p.scale);
        } else if (n < 2 * EDIM) {
          u16* dst = p.qk + (long)b * 4194304 + 2097152 + (long)l0 * 1024 + (n - EDIM);
#pragma unroll
          for (int r = 0; r < 4; ++r) dst[r * 1024] = f2h(acc[i][j][r]);
        } else {  // vT[b][n-2048][l0..l0+3] -- 8B packed store
          u16* dst = p.vT + (long)b * 1048576 + (long)(n - 2 * EDIM) * 2048 + l0;
          u32x2 w = {pk(acc[i][j][0], acc[i][j][1]), pk(acc[i][j][2], acc[i][j][3])};
          *(u32x2*)dst = w;
        }
      } else if constexpr (EPI == 3) {  // +bias +resid, f16 out (ff2), ld 512
        float bias = p.bias[n];
        u16* dst = p.Cb + (long)mb * 512 + n;
        const u16* rs = p.resid + (long)mb * 512 + n;
#pragma unroll
        for (int r = 0; r < 4; ++r) dst[r * 512] = f2h(acc[i][j][r] + bias + h2f(rs[r * 512]));
      } else {  // EPI 4: plain f16 (PV)
        u16* dst = p.Cb + (long)z * p.bsC + (long)mb * p.ldc + n;
#pragma unroll
        for (int r = 0; r < 4; ++r) dst[(long)r * p.ldc] = f2h(acc[i][j][r]);
      }
    }
  }
}

// =======================================================================
// 256x256 tile, BK=64, 8 waves, covered 2-phase (round-9 measured best
// for scores / ff1).
// =======================================================================
template <int EPI>
__global__ __launch_bounds__(512, 2) void gemm256(GemmP p) {
  __shared__ __align__(16) char lds[131072];
  const int tid = threadIdx.x;
  const int lane = tid & 63;
  const int wave = tid >> 6;
  const int wm = wave >> 2, wn = wave & 3;   // 2 x 4 waves
  const int bn0 = blockIdx.x * 256;
  const int bm0 = blockIdx.y * 256;
  const int z = blockIdx.z;

  const u16* gA[4]; const u16* gB[4];
  int ldsA[4], ldsB[4];
  {
    const u16* Ab = p.A + (long)z * p.bsA + (long)bm0 * p.lda;
    const u16* Bb = p.B + (long)z * p.bsB + (long)bn0 * p.ldb;
#pragma unroll
    for (int i = 0; i < 4; ++i) {
      int ch = i * 512 + tid;
      int row = ch >> 3, s = ch & 7;
      int ks = ((s ^ (row & 7)) << 3);
      gA[i] = Ab + (long)row * p.lda + ks;
      gB[i] = Bb + (long)row * p.ldb + ks;
      ldsA[i] = ch * 16;
      ldsB[i] = 32768 + ch * 16;
    }
  }
  auto stage = [&](int buf) {
    char* dst = lds + buf * 65536;
#pragma unroll
    for (int i = 0; i < 4; ++i) {
      __builtin_amdgcn_global_load_lds(
          (const __attribute__((address_space(1))) u32*)gA[i],
          (__attribute__((address_space(3))) u32*)(dst + ldsA[i]), 16, 0, 0);
      gA[i] += 64;
    }
#pragma unroll
    for (int i = 0; i < 4; ++i) {
      __builtin_amdgcn_global_load_lds(
          (const __attribute__((address_space(1))) u32*)gB[i],
          (__attribute__((address_space(3))) u32*)(dst + ldsB[i]), 16, 0, 0);
      gB[i] += 64;
    }
  };

  int abase[2], bbase[2];
  {
    int rA = wm * 128 + (lane & 15);
    int sA = (lane >> 4) ^ (lane & 7);
    abase[0] = rA * 128 + (sA << 4);
    abase[1] = abase[0] ^ 64;
    int rB = wn * 64 + (lane & 15);
    int sB = (lane >> 4) ^ (lane & 7);
    bbase[0] = 32768 + rB * 128 + (sB << 4);
    bbase[1] = bbase[0] ^ 64;
  }

  f32x4 acc[8][4] = {};
  stage(0);
  const int nk = p.K >> 6;
  int cur = 0;
  for (int kt = 0; kt < nk; ++kt) {
    __syncthreads();
    if (kt + 1 < nk) stage(cur ^ 1);
    const char* base = lds + cur * 65536;
#pragma unroll
    for (int h = 0; h < 2; ++h) {
      f16x8 av[8], bv[4];
#pragma unroll
      for (int m = 0; m < 8; ++m) av[m] = *(const f16x8*)(base + abase[h] + m * 2048);
#pragma unroll
      for (int j = 0; j < 4; ++j) bv[j] = *(const f16x8*)(base + bbase[h] + j * 2048);
#pragma unroll
      for (int m = 0; m < 8; ++m)
#pragma unroll
        for (int j = 0; j < 4; ++j)
          acc[m][j] = __builtin_amdgcn_mfma_f32_16x16x32_f16(av[m], bv[j], acc[m][j], 0, 0, 0);
    }
    cur ^= 1;
  }

#pragma unroll
  for (int i = 0; i < 8; ++i) {
#pragma unroll
    for (int j = 0; j < 4; ++j) {
      int mb = bm0 + wm * 128 + i * 16 + ((lane >> 4) << 2);
      int n = bn0 + wn * 64 + j * 16 + (lane & 15);
      if constexpr (EPI == 2) {  // +bias, relu, f16 out (ff1)
        u16* dst = p.Cb + (long)mb * p.ldc + n;
        float bias = p.bias[n];
#pragma unroll
        for (int r = 0; r < 4; ++r) dst[(long)r * p.ldc] = f2h(fmaxf(acc[i][j][r] + bias, 0.f));
      } else {  // EPI 4: plain f16 (scores)
        u16* dst = p.Cb + (long)z * p.bsC + (long)mb * p.ldc + n;
#pragma unroll
        for (int r = 0; r < 4; ++r) dst[(long)r * p.ldc] = f2h(acc[i][j][r]);
      }
    }
  }
}

// ---------- row softmax: 1 WAVE / row of 2048 f16 -> f16 weights ----------
// 64 lanes x 32 elems; pure __shfl_xor reductions, no LDS, no barriers.
__global__ __launch_bounds__(256) void softmax_rows(const u16* __restrict__ S,
                                                    u16* __restrict__ W, int b0) {
  int row = blockIdx.x * 4 + (threadIdx.x >> 6);   // row among bpl*2048
  int lane = threadIdx.x & 63;
  int z = row >> 11, l = row & 2047;
  const u16* x = S + (long)row * 2048 + lane * 32;
  u32x4 raw[4];
#pragma unroll
  for (int c = 0; c < 4; ++c) raw[c] = ((const u32x4*)x)[c];
  float e[32];
#pragma unroll
  for (int c = 0; c < 4; ++c)
#pragma unroll
    for (int q = 0; q < 4; ++q) {
      e[c * 8 + 2 * q] = h2f((u16)(raw[c][q] & 0xffff));
      e[c * 8 + 2 * q + 1] = h2f((u16)(raw[c][q] >> 16));
    }
  float m = e[0];
#pragma unroll
  for (int q = 1; q < 32; ++q) m = fmaxf(m, e[q]);
#pragma unroll
  for (int off = 32; off; off >>= 1) m = fmaxf(m, __shfl_xor(m, off));
  float s = 0.f;
#pragma unroll
  for (int q = 0; q < 32; ++q) { e[q] = __expf(e[q] - m); s += e[q]; }
#pragma unroll
  for (int off = 32; off; off >>= 1) s += __shfl_xor(s, off);
  float inv = 1.f / s;
  u16* dst = W + (long)(b0 + z) * 4194304 + (long)l * 2048 + lane * 32;
#pragma unroll
  for (int c = 0; c < 4; ++c) {
    u32x4 o = {pk(e[c * 8 + 0] * inv, e[c * 8 + 1] * inv),
               pk(e[c * 8 + 2] * inv, e[c * 8 + 3] * inv),
               pk(e[c * 8 + 4] * inv, e[c * 8 + 5] * inv),
               pk(e[c * 8 + 6] * inv, e[c * 8 + 7] * inv)};
    ((u32x4*)dst)[c] = o;
  }
}

// ---------- LayerNorm over 512, wave per row ----------
template <int INF16, int OUTF16>
__global__ __launch_bounds__(256) void ln_rows(const void* __restrict__ X,
                                               const float* __restrict__ g,
                                               const float* __restrict__ bb,
                                               void* __restrict__ out) {
  int row = blockIdx.x * 4 + (threadIdx.x >> 6);
  int lane = threadIdx.x & 63;
  float v[8];
  if constexpr (INF16) {
    u32x4 raw = *(const u32x4*)((const u16*)X + (long)row * 512 + lane * 8);
#pragma unroll
    for (int q = 0; q < 4; ++q) {
      v[2 * q] = h2f((u16)(raw[q] & 0xffff));
      v[2 * q + 1] = h2f((u16)(raw[q] >> 16));
    }
  } else {
    const float* x = (const float*)X + (long)row * 512 + lane * 8;
    f32x4 a = *(const f32x4*)x, b = *(const f32x4*)(x + 4);
#pragma unroll
    for (int q = 0; q < 4; ++q) { v[q] = a[q]; v[4 + q] = b[q]; }
  }
  float s = 0.f, sq = 0.f;
#pragma unroll
  for (int q = 0; q < 8; ++q) { s += v[q]; sq += v[q] * v[q]; }
#pragma unroll
  for (int off = 32; off; off >>= 1) {
    s += __shfl_xor(s, off);
    sq += __shfl_xor(sq, off);
  }
  float mean = s * (1.f / 512.f);
  float var = sq * (1.f / 512.f) - mean * mean;
  float rstd = rsqrtf(var + 1e-5f);
  f32x4 g0 = *(const f32x4*)(g + lane * 8), g1v = *(const f32x4*)(g + lane * 8 + 4);
  f32x4 b0 = *(const f32x4*)(bb + lane * 8), b1v = *(const f32x4*)(bb + lane * 8 + 4);
  float o[8];
#pragma unroll
  for (int q = 0; q < 4; ++q) o[q] = (v[q] - mean) * rstd * g0[q] + b0[q];
#pragma unroll
  for (int q = 0; q < 4; ++q) o[4 + q] = (v[4 + q] - mean) * rstd * g1v[q] + b1v[q];
  if constexpr (OUTF16) {
    u32x4 pkd = {pk(o[0], o[1]), pk(o[2], o[3]), pk(o[4], o[5]), pk(o[6], o[7])};
    *(u32x4*)((u16*)out + (long)row * 512 + lane * 8) = pkd;
  } else {
    float* dst = (float*)out + (long)row * 512 + lane * 8;
    *(f32x4*)dst = (f32x4){o[0], o[1], o[2], o[3]};
    *(f32x4*)(dst + 4) = (f32x4){o[4], o[5], o[6], o[7]};
  }
}

// ---------- launch ----------
extern "C" void kernel_launch(void* const* d_in, const int* in_sizes, int n_in,
                              void* d_out, int out_size, void* d_ws, size_t ws_size,
                              hipStream_t stream) {
  const float* x = (const float*)d_in[0];
  const float* wp = (const float*)d_in[1];
  const float* w1 = (const float*)d_in[2];
  const float* b1 = (const float*)d_in[3];
  const float* w2 = (const float*)d_in[4];
  const float* b2 = (const float*)d_in[5];
  const float* g1 = (const float*)d_in[6];
  const float* be1 = (const float*)d_in[7];
  const float* g2 = (const float*)d_in[8];
  const float* be2 = (const float*)d_in[9];

  char* ws = (char*)d_ws;
  size_t off = 0;
  auto alloc = [&](size_t bytes) {
    char* p = ws + off;
    off += (bytes + 255) & ~(size_t)255;
    return p;
  };
  u16* wpb = (u16*)alloc(2560 * 1024 * 2);
  u16* w1b = (u16*)alloc(2048 * 512 * 2);
  u16* w2b = (u16*)alloc(512 * 2048 * 2);
  char* xb_region = alloc(33554432);            // x f16 -> attn_out f16
  u16* qk = (u16*)alloc(67108864);              // [q|k] f16 -> attnw -> ff1
  u16* vT = (u16*)alloc(16777216);              // v transposed f16
  u16* hb = (u16*)alloc(16777216);              // h f16
  int bpl = (ws_size >= off + (size_t)67108864) ? 8 : 4;
  char* sc_region = alloc((size_t)bpl * 2048 * 2048 * 2);
  if (off > ws_size) return;

  u16* xb = (u16*)xb_region;
  u16* attn16 = (u16*)xb_region;
  u16* scores = (u16*)sc_region;
  u16* y16 = (u16*)sc_region;
  u16* ff1 = qk;

  const float SC = (float)(0.03125 * 2.0 * 7.6246189861593985);

  cvt_all<<<dim3(10496), dim3(256), 0, stream>>>(x, xb, wp, wpb, w1, w1b, w2, w2b);

  {  // proj: (16384x1024) @ (2560x1024)^T  [128^2 BK=64 covered]
    GemmP p{};
    p.A = xb; p.lda = 1024; p.B = wpb; p.ldb = 1024; p.K = 1024;
    p.qk = qk; p.vT = vT; p.scale = SC;
    gemm_bt<1><<<dim3(20, 128, 1), 256, 0, stream>>>(p);
  }

  for (int it = 0; it < 8 / bpl; ++it) {  // scores + softmax  [256^2 covered]
    int b0 = it * bpl;
    GemmP p{};
    p.A = qk + (long)b0 * 4194304; p.lda = 1024; p.bsA = 4194304;
    p.B = qk + (long)b0 * 4194304 + 2097152; p.ldb = 1024; p.bsB = 4194304;
    p.K = 1024; p.Cb = scores; p.ldc = 2048; p.bsC = 4194304;
    gemm256<4><<<dim3(8, 8, bpl), 512, 0, stream>>>(p);
    softmax_rows<<<dim3(bpl * 512), dim3(256), 0, stream>>>(scores, qk, b0);
  }

  {  // PV: attnw(2048x2048) @ vT(512x2048)^T -> f16  [128^2 BK=64 covered]
    GemmP p{};
    p.A = qk; p.lda = 2048; p.bsA = 4194304;
    p.B = vT; p.ldb = 2048; p.bsB = 1048576;
    p.K = 2048; p.Cb = attn16; p.ldc = 512; p.bsC = 1048576;
    gemm_bt<4><<<dim3(4, 16, 8), 256, 0, stream>>>(p);
  }

  ln_rows<1, 1><<<dim3(4096), dim3(256), 0, stream>>>(attn16, g1, be1, hb);

  {  // ff1: h(16384x512) @ w1(2048x512)^T, +b1 relu -> f16  [256^2 covered]
    GemmP p{};
    p.A = hb; p.lda = 512; p.B = w1b; p.ldb = 512; p.K = 512;
    p.Cb = ff1; p.ldc = 2048; p.bias = b1;
    gemm256<2><<<dim3(8, 64, 1), 512, 0, stream>>>(p);
  }

  {  // ff2: ff1(16384x2048) @ w2(512x2048)^T, +b2 +h -> f16  [128^2 BK=64]
    GemmP p{};
    p.A = ff1; p.lda = 2048; p.B = w2b; p.ldb = 2048; p.K = 2048;
    p.Cb = y16; p.bias = b2; p.resid = hb;
    gemm_bt<3><<<dim3(4, 128, 1), 256, 0, stream>>>(p);
  }

  ln_rows<1, 0><<<dim3(4096), dim3(256), 0, stream>>>(y16, g2, be2, (float*)d_out);
}

// Round 12
// 376.289 us; speedup vs baseline: 1.0267x; 1.0267x over previous
//
#include <hip/hip_runtime.h>
#include <hip/hip_bf16.h>

// ---------- types ----------
typedef unsigned short u16;
typedef unsigned int u32;
typedef float f32x4 __attribute__((ext_vector_type(4)));
typedef _Float16 f16x8 __attribute__((ext_vector_type(8)));
typedef u32 u32x4 __attribute__((ext_vector_type(4)));
typedef u32 u32x2 __attribute__((ext_vector_type(2)));

#define SEQ 2048
#define EDIM 1024

__device__ __forceinline__ u16 f2h(float f) {
  _Float16 h = (_Float16)f;
  return __builtin_bit_cast(u16, h);
}
__device__ __forceinline__ float h2f(u16 u) {
  return (float)__builtin_bit_cast(_Float16, u);
}
__device__ __forceinline__ u32 pk(float a, float b) {
  return (u32)f2h(a) | ((u32)f2h(b) << 16);
}

// ---------- fused fp32 -> fp16 convert for all 4 inputs, 8 elems/thread ----
#define N_X  2097152
#define N_WP 327680
#define N_W1 131072
#define N_W2 131072
__global__ __launch_bounds__(256) void cvt_all(const float* __restrict__ x, u16* __restrict__ xb,
                                               const float* __restrict__ wp, u16* __restrict__ wpb,
                                               const float* __restrict__ w1, u16* __restrict__ w1b,
                                               const float* __restrict__ w2, u16* __restrict__ w2b) {
  int i = blockIdx.x * 256 + threadIdx.x;
  const float* src; u16* dst; int li;
  if (i < N_X) { src = x; dst = xb; li = i; }
  else if (i < N_X + N_WP) { src = wp; dst = wpb; li = i - N_X; }
  else if (i < N_X + N_WP + N_W1) { src = w1; dst = w1b; li = i - N_X - N_WP; }
  else if (i < N_X + N_WP + N_W1 + N_W2) { src = w2; dst = w2b; li = i - N_X - N_WP - N_W1; }
  else return;
  const f32x4* p = (const f32x4*)(src + (size_t)li * 8);
  f32x4 a = p[0], b = p[1];
  u32x4 o = {pk(a[0], a[1]), pk(a[2], a[3]), pk(b[0], b[1]), pk(b[2], b[3])};
  *(u32x4*)(dst + (size_t)li * 8) = o;
}

struct GemmP {
  const u16* A; const u16* B;
  int lda, ldb, K;
  long bsA, bsB, bsC;       // per-blockIdx.z element strides
  int ldc;
  u16* Cb;                  // f16 store
  const float* bias;        // EPI 2,3
  const u16* resid;         // EPI 3 (h, f16, ld 512)
  u16* qk; u16* vT;         // EPI 1 (proj split)
  float scale;              // EPI 1
};

// =======================================================================
// 128x128 tile, BK=64, 4 waves (2x2), 16x16x32 f16 MFMA, COVERED-STAGING
// 2-phase double-buffer (round-8 proven best: proj 100.3us / MfmaUtil 38.2).
// LDS 64KB -> 2 blocks/CU. Used for proj, PV, ff2.
// EPI: 1 = proj split (q*SC | k | vT), 3 = +bias +resid f16 (ff2),
//      4 = plain f16 (PV).
// =======================================================================
template <int EPI>
__global__ __launch_bounds__(256) void gemm_bt(GemmP p) {
  __shared__ __align__(16) char lds[65536];
  const int tid = threadIdx.x;
  const int lane = tid & 63;
  const int wave = tid >> 6;
  const int wm = wave >> 1, wn = wave & 1;
  const int bn0 = blockIdx.x * 128;
  const int bm0 = blockIdx.y * 128;
  const int z = blockIdx.z;

  const u16* gA[4]; const u16* gB[4];
  int ldsA[4], ldsB[4];
  {
    const u16* Ab = p.A + (long)z * p.bsA + (long)bm0 * p.lda;
    const u16* Bb = p.B + (long)z * p.bsB + (long)bn0 * p.ldb;
#pragma unroll
    for (int i = 0; i < 4; ++i) {
      int ch = i * 256 + tid;
      int row = ch >> 3, s = ch & 7;
      int ks = ((s ^ (row & 7)) << 3);  // inverse-swizzled global source
      gA[i] = Ab + (long)row * p.lda + ks;
      gB[i] = Bb + (long)row * p.ldb + ks;
      ldsA[i] = ch * 16;
      ldsB[i] = 16384 + ch * 16;
    }
  }
  auto stage = [&](int buf) {
    char* dst = lds + buf * 32768;
#pragma unroll
    for (int i = 0; i < 4; ++i) {
      __builtin_amdgcn_global_load_lds(
          (const __attribute__((address_space(1))) u32*)gA[i],
          (__attribute__((address_space(3))) u32*)(dst + ldsA[i]), 16, 0, 0);
      gA[i] += 64;
    }
#pragma unroll
    for (int i = 0; i < 4; ++i) {
      __builtin_amdgcn_global_load_lds(
          (const __attribute__((address_space(1))) u32*)gB[i],
          (__attribute__((address_space(3))) u32*)(dst + ldsB[i]), 16, 0, 0);
      gB[i] += 64;
    }
  };

  int ao[2][4], bo[2][4];
#pragma unroll
  for (int h = 0; h < 2; ++h) {
#pragma unroll
    for (int i = 0; i < 4; ++i) {
      int rA = wm * 64 + i * 16 + (lane & 15);
      ao[h][i] = rA * 128 + ((((h << 2) | (lane >> 4)) ^ (rA & 7)) << 4);
      int rB = wn * 64 + i * 16 + (lane & 15);
      bo[h][i] = 16384 + rB * 128 + ((((h << 2) | (lane >> 4)) ^ (rB & 7)) << 4);
    }
  }

  f32x4 acc[4][4] = {};
  stage(0);
  const int nk = p.K >> 6;
  int cur = 0;
  for (int kt = 0; kt < nk; ++kt) {
    __syncthreads();                  // buf[cur] landed; drain covered by prev tile
    if (kt + 1 < nk) stage(cur ^ 1);  // issue next tile FIRST
    const char* base = lds + cur * 32768;
#pragma unroll
    for (int h = 0; h < 2; ++h) {
      f16x8 av[4], bv[4];
#pragma unroll
      for (int i = 0; i < 4; ++i) av[i] = *(const f16x8*)(base + ao[h][i]);
#pragma unroll
      for (int j = 0; j < 4; ++j) bv[j] = *(const f16x8*)(base + bo[h][j]);
#pragma unroll
      for (int i = 0; i < 4; ++i)
#pragma unroll
        for (int j = 0; j < 4; ++j)
          acc[i][j] = __builtin_amdgcn_mfma_f32_16x16x32_f16(av[i], bv[j], acc[i][j], 0, 0, 0);
    }
    cur ^= 1;
  }

  // epilogue: C row = (lane>>4)*4+reg, col = lane&15 (m89 layout)
#pragma unroll
  for (int i = 0; i < 4; ++i) {
#pragma unroll
    for (int j = 0; j < 4; ++j) {
      int mb = bm0 + wm * 64 + i * 16 + ((lane >> 4) << 2);
      int n = bn0 + wn * 64 + j * 16 + (lane & 15);
      if constexpr (EPI == 1) {  // proj split into q*SCALE | k | vT
        int b = mb >> 11, l0 = mb & 2047;
        if (n < EDIM) {
          u16* dst = p.qk + (long)b * 4194304 + (long)l0 * 1024 + n;
#pragma unroll
          for (int r = 0; r < 4; ++r) dst[r * 1024] = f2h(acc[i][j][r] * p.scale);
        } else if (n < 2 * EDIM) {
          u16* dst = p.qk + (long)b * 4194304 + 2097152 + (long)l0 * 1024 + (n - EDIM);
#pragma unroll
          for (int r = 0; r < 4; ++r) dst[r * 1024] = f2h(acc[i][j][r]);
        } else {  // vT[b][n-2048][l0..l0+3] -- 8B packed store
          u16* dst = p.vT + (long)b * 1048576 + (long)(n - 2 * EDIM) * 2048 + l0;
          u32x2 w = {pk(acc[i][j][0], acc[i][j][1]), pk(acc[i][j][2], acc[i][j][3])};
          *(u32x2*)dst = w;
        }
      } else if constexpr (EPI == 3) {  // +bias +resid, f16 out (ff2), ld 512
        float bias = p.bias[n];
        u16* dst = p.Cb + (long)mb * 512 + n;
        const u16* rs = p.resid + (long)mb * 512 + n;
#pragma unroll
        for (int r = 0; r < 4; ++r) dst[r * 512] = f2h(acc[i][j][r] + bias + h2f(rs[r * 512]));
      } else {  // EPI 4: plain f16 (PV)
        u16* dst = p.Cb + (long)z * p.bsC + (long)mb * p.ldc + n;
#pragma unroll
        for (int r = 0; r < 4; ++r) dst[(long)r * p.ldc] = f2h(acc[i][j][r]);
      }
    }
  }
}

// =======================================================================
// 256x256 tile, BK=64, 8 waves, covered 2-phase (round-9 measured best
// for scores / ff1).
// =======================================================================
template <int EPI>
__global__ __launch_bounds__(512, 2) void gemm256(GemmP p) {
  __shared__ __align__(16) char lds[131072];
  const int tid = threadIdx.x;
  const int lane = tid & 63;
  const int wave = tid >> 6;
  const int wm = wave >> 2, wn = wave & 3;   // 2 x 4 waves
  const int bn0 = blockIdx.x * 256;
  const int bm0 = blockIdx.y * 256;
  const int z = blockIdx.z;

  const u16* gA[4]; const u16* gB[4];
  int ldsA[4], ldsB[4];
  {
    const u16* Ab = p.A + (long)z * p.bsA + (long)bm0 * p.lda;
    const u16* Bb = p.B + (long)z * p.bsB + (long)bn0 * p.ldb;
#pragma unroll
    for (int i = 0; i < 4; ++i) {
      int ch = i * 512 + tid;
      int row = ch >> 3, s = ch & 7;
      int ks = ((s ^ (row & 7)) << 3);
      gA[i] = Ab + (long)row * p.lda + ks;
      gB[i] = Bb + (long)row * p.ldb + ks;
      ldsA[i] = ch * 16;
      ldsB[i] = 32768 + ch * 16;
    }
  }
  auto stage = [&](int buf) {
    char* dst = lds + buf * 65536;
#pragma unroll
    for (int i = 0; i < 4; ++i) {
      __builtin_amdgcn_global_load_lds(
          (const __attribute__((address_space(1))) u32*)gA[i],
          (__attribute__((address_space(3))) u32*)(dst + ldsA[i]), 16, 0, 0);
      gA[i] += 64;
    }
#pragma unroll
    for (int i = 0; i < 4; ++i) {
      __builtin_amdgcn_global_load_lds(
          (const __attribute__((address_space(1))) u32*)gB[i],
          (__attribute__((address_space(3))) u32*)(dst + ldsB[i]), 16, 0, 0);
      gB[i] += 64;
    }
  };

  int abase[2], bbase[2];
  {
    int rA = wm * 128 + (lane & 15);
    int sA = (lane >> 4) ^ (lane & 7);
    abase[0] = rA * 128 + (sA << 4);
    abase[1] = abase[0] ^ 64;
    int rB = wn * 64 + (lane & 15);
    int sB = (lane >> 4) ^ (lane & 7);
    bbase[0] = 32768 + rB * 128 + (sB << 4);
    bbase[1] = bbase[0] ^ 64;
  }

  f32x4 acc[8][4] = {};
  stage(0);
  const int nk = p.K >> 6;
  int cur = 0;
  for (int kt = 0; kt < nk; ++kt) {
    __syncthreads();
    if (kt + 1 < nk) stage(cur ^ 1);
    const char* base = lds + cur * 65536;
#pragma unroll
    for (int h = 0; h < 2; ++h) {
      f16x8 av[8], bv[4];
#pragma unroll
      for (int m = 0; m < 8; ++m) av[m] = *(const f16x8*)(base + abase[h] + m * 2048);
#pragma unroll
      for (int j = 0; j < 4; ++j) bv[j] = *(const f16x8*)(base + bbase[h] + j * 2048);
#pragma unroll
      for (int m = 0; m < 8; ++m)
#pragma unroll
        for (int j = 0; j < 4; ++j)
          acc[m][j] = __builtin_amdgcn_mfma_f32_16x16x32_f16(av[m], bv[j], acc[m][j], 0, 0, 0);
    }
    cur ^= 1;
  }

#pragma unroll
  for (int i = 0; i < 8; ++i) {
#pragma unroll
    for (int j = 0; j < 4; ++j) {
      int mb = bm0 + wm * 128 + i * 16 + ((lane >> 4) << 2);
      int n = bn0 + wn * 64 + j * 16 + (lane & 15);
      if constexpr (EPI == 2) {  // +bias, relu, f16 out (ff1)
        u16* dst = p.Cb + (long)mb * p.ldc + n;
        float bias = p.bias[n];
#pragma unroll
        for (int r = 0; r < 4; ++r) dst[(long)r * p.ldc] = f2h(fmaxf(acc[i][j][r] + bias, 0.f));
      } else {  // EPI 4: plain f16 (scores)
        u16* dst = p.Cb + (long)z * p.bsC + (long)mb * p.ldc + n;
#pragma unroll
        for (int r = 0; r < 4; ++r) dst[(long)r * p.ldc] = f2h(acc[i][j][r]);
      }
    }
  }
}

// ---------- row softmax: 1 WAVE / row of 2048 f16 -> f16 weights ----------
// 64 lanes; per-lane data = 4 chunk-interleaved 16B vectors at
// c*512 + lane*8 (each chunk: 64 lanes x 16B = contiguous 1KB, coalesced).
// Pure __shfl_xor reductions, no LDS, no barriers; reductions are
// order-agnostic so the lane->element permutation is free.
__global__ __launch_bounds__(256) void softmax_rows(const u16* __restrict__ S,
                                                    u16* __restrict__ W, int b0) {
  int row = blockIdx.x * 4 + (threadIdx.x >> 6);   // row among bpl*2048
  int lane = threadIdx.x & 63;
  int z = row >> 11, l = row & 2047;
  const u16* x = S + (long)row * 2048;
  u32x4 raw[4];
#pragma unroll
  for (int c = 0; c < 4; ++c) raw[c] = *(const u32x4*)(x + c * 512 + lane * 8);
  float e[32];
#pragma unroll
  for (int c = 0; c < 4; ++c)
#pragma unroll
    for (int q = 0; q < 4; ++q) {
      e[c * 8 + 2 * q] = h2f((u16)(raw[c][q] & 0xffff));
      e[c * 8 + 2 * q + 1] = h2f((u16)(raw[c][q] >> 16));
    }
  float m = e[0];
#pragma unroll
  for (int q = 1; q < 32; ++q) m = fmaxf(m, e[q]);
#pragma unroll
  for (int off = 32; off; off >>= 1) m = fmaxf(m, __shfl_xor(m, off));
  float s = 0.f;
#pragma unroll
  for (int q = 0; q < 32; ++q) { e[q] = __expf(e[q] - m); s += e[q]; }
#pragma unroll
  for (int off = 32; off; off >>= 1) s += __shfl_xor(s, off);
  float inv = 1.f / s;
  u16* dst = W + (long)(b0 + z) * 4194304 + (long)l * 2048;
#pragma unroll
  for (int c = 0; c < 4; ++c) {
    u32x4 o = {pk(e[c * 8 + 0] * inv, e[c * 8 + 1] * inv),
               pk(e[c * 8 + 2] * inv, e[c * 8 + 3] * inv),
               pk(e[c * 8 + 4] * inv, e[c * 8 + 5] * inv),
               pk(e[c * 8 + 6] * inv, e[c * 8 + 7] * inv)};
    *(u32x4*)(dst + c * 512 + lane * 8) = o;
  }
}

// ---------- LayerNorm over 512, wave per row ----------
template <int INF16, int OUTF16>
__global__ __launch_bounds__(256) void ln_rows(const void* __restrict__ X,
                                               const float* __restrict__ g,
                                               const float* __restrict__ bb,
                                               void* __restrict__ out) {
  int row = blockIdx.x * 4 + (threadIdx.x >> 6);
  int lane = threadIdx.x & 63;
  float v[8];
  if constexpr (INF16) {
    u32x4 raw = *(const u32x4*)((const u16*)X + (long)row * 512 + lane * 8);
#pragma unroll
    for (int q = 0; q < 4; ++q) {
      v[2 * q] = h2f((u16)(raw[q] & 0xffff));
      v[2 * q + 1] = h2f((u16)(raw[q] >> 16));
    }
  } else {
    const float* x = (const float*)X + (long)row * 512 + lane * 8;
    f32x4 a = *(const f32x4*)x, b = *(const f32x4*)(x + 4);
#pragma unroll
    for (int q = 0; q < 4; ++q) { v[q] = a[q]; v[4 + q] = b[q]; }
  }
  float s = 0.f, sq = 0.f;
#pragma unroll
  for (int q = 0; q < 8; ++q) { s += v[q]; sq += v[q] * v[q]; }
#pragma unroll
  for (int off = 32; off; off >>= 1) {
    s += __shfl_xor(s, off);
    sq += __shfl_xor(sq, off);
  }
  float mean = s * (1.f / 512.f);
  float var = sq * (1.f / 512.f) - mean * mean;
  float rstd = rsqrtf(var + 1e-5f);
  f32x4 g0 = *(const f32x4*)(g + lane * 8), g1v = *(const f32x4*)(g + lane * 8 + 4);
  f32x4 b0 = *(const f32x4*)(bb + lane * 8), b1v = *(const f32x4*)(bb + lane * 8 + 4);
  float o[8];
#pragma unroll
  for (int q = 0; q < 4; ++q) o[q] = (v[q] - mean) * rstd * g0[q] + b0[q];
#pragma unroll
  for (int q = 0; q < 4; ++q) o[4 + q] = (v[4 + q] - mean) * rstd * g1v[q] + b1v[q];
  if constexpr (OUTF16) {
    u32x4 pkd = {pk(o[0], o[1]), pk(o[2], o[3]), pk(o[4], o[5]), pk(o[6], o[7])};
    *(u32x4*)((u16*)out + (long)row * 512 + lane * 8) = pkd;
  } else {
    float* dst = (float*)out + (long)row * 512 + lane * 8;
    *(f32x4*)dst = (f32x4){o[0], o[1], o[2], o[3]};
    *(f32x4*)(dst + 4) = (f32x4){o[4], o[5], o[6], o[7]};
  }
}

// ---------- launch ----------
extern "C" void kernel_launch(void* const* d_in, const int* in_sizes, int n_in,
                              void* d_out, int out_size, void* d_ws, size_t ws_size,
                              hipStream_t stream) {
  const float* x = (const float*)d_in[0];
  const float* wp = (const float*)d_in[1];
  const float* w1 = (const float*)d_in[2];
  const float* b1 = (const float*)d_in[3];
  const float* w2 = (const float*)d_in[4];
  const float* b2 = (const float*)d_in[5];
  const float* g1 = (const float*)d_in[6];
  const float* be1 = (const float*)d_in[7];
  const float* g2 = (const float*)d_in[8];
  const float* be2 = (const float*)d_in[9];

  char* ws = (char*)d_ws;
  size_t off = 0;
  auto alloc = [&](size_t bytes) {
    char* p = ws + off;
    off += (bytes + 255) & ~(size_t)255;
    return p;
  };
  u16* wpb = (u16*)alloc(2560 * 1024 * 2);
  u16* w1b = (u16*)alloc(2048 * 512 * 2);
  u16* w2b = (u16*)alloc(512 * 2048 * 2);
  char* xb_region = alloc(33554432);            // x f16 -> attn_out f16
  u16* qk = (u16*)alloc(67108864);              // [q|k] f16 -> attnw -> ff1
  u16* vT = (u16*)alloc(16777216);              // v transposed f16
  u16* hb = (u16*)alloc(16777216);              // h f16
  int bpl = (ws_size >= off + (size_t)67108864) ? 8 : 4;
  char* sc_region = alloc((size_t)bpl * 2048 * 2048 * 2);
  if (off > ws_size) return;

  u16* xb = (u16*)xb_region;
  u16* attn16 = (u16*)xb_region;
  u16* scores = (u16*)sc_region;
  u16* y16 = (u16*)sc_region;
  u16* ff1 = qk;

  const float SC = (float)(0.03125 * 2.0 * 7.6246189861593985);

  cvt_all<<<dim3(10496), dim3(256), 0, stream>>>(x, xb, wp, wpb, w1, w1b, w2, w2b);

  {  // proj: (16384x1024) @ (2560x1024)^T  [128^2 BK=64 covered]
    GemmP p{};
    p.A = xb; p.lda = 1024; p.B = wpb; p.ldb = 1024; p.K = 1024;
    p.qk = qk; p.vT = vT; p.scale = SC;
    gemm_bt<1><<<dim3(20, 128, 1), 256, 0, stream>>>(p);
  }

  for (int it = 0; it < 8 / bpl; ++it) {  // scores + softmax  [256^2 covered]
    int b0 = it * bpl;
    GemmP p{};
    p.A = qk + (long)b0 * 4194304; p.lda = 1024; p.bsA = 4194304;
    p.B = qk + (long)b0 * 4194304 + 2097152; p.ldb = 1024; p.bsB = 4194304;
    p.K = 1024; p.Cb = scores; p.ldc = 2048; p.bsC = 4194304;
    gemm256<4><<<dim3(8, 8, bpl), 512, 0, stream>>>(p);
    softmax_rows<<<dim3(bpl * 512), dim3(256), 0, stream>>>(scores, qk, b0);
  }

  {  // PV: attnw(2048x2048) @ vT(512x2048)^T -> f16  [128^2 BK=64 covered]
    GemmP p{};
    p.A = qk; p.lda = 2048; p.bsA = 4194304;
    p.B = vT; p.ldb = 2048; p.bsB = 1048576;
    p.K = 2048; p.Cb = attn16; p.ldc = 512; p.bsC = 1048576;
    gemm_bt<4><<<dim3(4, 16, 8), 256, 0, stream>>>(p);
  }

  ln_rows<1, 1><<<dim3(4096), dim3(256), 0, stream>>>(attn16, g1, be1, hb);

  {  // ff1: h(16384x512) @ w1(2048x512)^T, +b1 relu -> f16  [256^2 covered]
    GemmP p{};
    p.A = hb; p.lda = 512; p.B = w1b; p.ldb = 512; p.K = 512;
    p.Cb = ff1; p.ldc = 2048; p.bias = b1;
    gemm256<2><<<dim3(8, 64, 1), 512, 0, stream>>>(p);
  }

  {  // ff2: ff1(16384x2048) @ w2(512x2048)^T, +b2 +h -> f16  [128^2 BK=64]
    GemmP p{};
    p.A = ff1; p.lda = 2048; p.B = w2b; p.ldb = 2048; p.K = 2048;
    p.Cb = y16; p.bias = b2; p.resid = hb;
    gemm_bt<3><<<dim3(4, 128, 1), 256, 0, stream>>>(p);
  }

  ln_rows<1, 0><<<dim3(4096), dim3(256), 0, stream>>>(y16, g2, be2, (float*)d_out);
}

// Round 13
// 351.580 us; speedup vs baseline: 1.0988x; 1.0703x over previous
//
#include <hip/hip_runtime.h>
#include <hip/hip_bf16.h>

// ---------- types ----------
typedef unsigned short u16;
typedef unsigned int u32;
typedef float f32x4 __attribute__((ext_vector_type(4)));
typedef _Float16 f16x8 __attribute__((ext_vector_type(8)));
typedef u32 u32x4 __attribute__((ext_vector_type(4)));
typedef u32 u32x2 __attribute__((ext_vector_type(2)));

#define SEQ 2048
#define EDIM 1024

__device__ __forceinline__ u16 f2h(float f) {
  _Float16 h = (_Float16)f;
  return __builtin_bit_cast(u16, h);
}
__device__ __forceinline__ float h2f(u16 u) {
  return (float)__builtin_bit_cast(_Float16, u);
}
__device__ __forceinline__ u32 pk(float a, float b) {
  return (u32)f2h(a) | ((u32)f2h(b) << 16);
}

// XCD-aware bijective block remap (T1, m157/m204): blocks sharing an A-panel
// (same y / same batch z) land on the SAME XCD's L2. Requires nwg % 8 == 0
// (all five GEMM grids: 2560, 512, 512, 512, 512).
__device__ __forceinline__ void xcd_remap(int& bx, int& by, int& bz) {
  int gx = gridDim.x, gy = gridDim.y;
  int lin = (blockIdx.z * gy + blockIdx.y) * gx + blockIdx.x;
  int nwg = gx * gy * gridDim.z;
  int nl = (lin & 7) * (nwg >> 3) + (lin >> 3);
  bx = nl % gx;
  int t = nl / gx;
  by = t % gy;
  bz = t / gy;
}

// ---------- fused fp32 -> fp16 convert for all 4 inputs, 8 elems/thread ----
#define N_X  2097152
#define N_WP 327680
#define N_W1 131072
#define N_W2 131072
__global__ __launch_bounds__(256) void cvt_all(const float* __restrict__ x, u16* __restrict__ xb,
                                               const float* __restrict__ wp, u16* __restrict__ wpb,
                                               const float* __restrict__ w1, u16* __restrict__ w1b,
                                               const float* __restrict__ w2, u16* __restrict__ w2b) {
  int i = blockIdx.x * 256 + threadIdx.x;
  const float* src; u16* dst; int li;
  if (i < N_X) { src = x; dst = xb; li = i; }
  else if (i < N_X + N_WP) { src = wp; dst = wpb; li = i - N_X; }
  else if (i < N_X + N_WP + N_W1) { src = w1; dst = w1b; li = i - N_X - N_WP; }
  else if (i < N_X + N_WP + N_W1 + N_W2) { src = w2; dst = w2b; li = i - N_X - N_WP - N_W1; }
  else return;
  const f32x4* p = (const f32x4*)(src + (size_t)li * 8);
  f32x4 a = p[0], b = p[1];
  u32x4 o = {pk(a[0], a[1]), pk(a[2], a[3]), pk(b[0], b[1]), pk(b[2], b[3])};
  *(u32x4*)(dst + (size_t)li * 8) = o;
}

struct GemmP {
  const u16* A; const u16* B;
  int lda, ldb, K;
  long bsA, bsB, bsC;       // per-z element strides
  int ldc;
  u16* Cb;                  // f16 store
  const float* bias;        // EPI 2,3
  const u16* resid;         // EPI 3 (h, f16, ld 512)
  u16* qk; u16* vT;         // EPI 1 (proj split)
  float scale;              // EPI 1
};

// =======================================================================
// 128x128 tile, BK=64, 4 waves (2x2), 16x16x32 f16 MFMA, COVERED-STAGING
// 2-phase double-buffer (round-8 proven: proj 100.3us / MfmaUtil 38.2).
// LDS 64KB -> 2 blocks/CU. + XCD remap (T1). Used for proj, PV, ff2.
// EPI: 1 = proj split (q*SC | k | vT), 3 = +bias +resid f16 (ff2),
//      4 = plain f16 (PV).
// =======================================================================
template <int EPI>
__global__ __launch_bounds__(256) void gemm_bt(GemmP p) {
  __shared__ __align__(16) char lds[65536];
  const int tid = threadIdx.x;
  const int lane = tid & 63;
  const int wave = tid >> 6;
  const int wm = wave >> 1, wn = wave & 1;
  int bxi, byi, bzi;
  xcd_remap(bxi, byi, bzi);
  const int bn0 = bxi * 128;
  const int bm0 = byi * 128;
  const int z = bzi;

  const u16* gA[4]; const u16* gB[4];
  int ldsA[4], ldsB[4];
  {
    const u16* Ab = p.A + (long)z * p.bsA + (long)bm0 * p.lda;
    const u16* Bb = p.B + (long)z * p.bsB + (long)bn0 * p.ldb;
#pragma unroll
    for (int i = 0; i < 4; ++i) {
      int ch = i * 256 + tid;
      int row = ch >> 3, s = ch & 7;
      int ks = ((s ^ (row & 7)) << 3);  // inverse-swizzled global source
      gA[i] = Ab + (long)row * p.lda + ks;
      gB[i] = Bb + (long)row * p.ldb + ks;
      ldsA[i] = ch * 16;
      ldsB[i] = 16384 + ch * 16;
    }
  }
  auto stage = [&](int buf) {
    char* dst = lds + buf * 32768;
#pragma unroll
    for (int i = 0; i < 4; ++i) {
      __builtin_amdgcn_global_load_lds(
          (const __attribute__((address_space(1))) u32*)gA[i],
          (__attribute__((address_space(3))) u32*)(dst + ldsA[i]), 16, 0, 0);
      gA[i] += 64;
    }
#pragma unroll
    for (int i = 0; i < 4; ++i) {
      __builtin_amdgcn_global_load_lds(
          (const __attribute__((address_space(1))) u32*)gB[i],
          (__attribute__((address_space(3))) u32*)(dst + ldsB[i]), 16, 0, 0);
      gB[i] += 64;
    }
  };

  int ao[2][4], bo[2][4];
#pragma unroll
  for (int h = 0; h < 2; ++h) {
#pragma unroll
    for (int i = 0; i < 4; ++i) {
      int rA = wm * 64 + i * 16 + (lane & 15);
      ao[h][i] = rA * 128 + ((((h << 2) | (lane >> 4)) ^ (rA & 7)) << 4);
      int rB = wn * 64 + i * 16 + (lane & 15);
      bo[h][i] = 16384 + rB * 128 + ((((h << 2) | (lane >> 4)) ^ (rB & 7)) << 4);
    }
  }

  f32x4 acc[4][4] = {};
  stage(0);
  const int nk = p.K >> 6;
  int cur = 0;
  for (int kt = 0; kt < nk; ++kt) {
    __syncthreads();                  // buf[cur] landed; drain covered by prev tile
    if (kt + 1 < nk) stage(cur ^ 1);  // issue next tile FIRST
    const char* base = lds + cur * 32768;
#pragma unroll
    for (int h = 0; h < 2; ++h) {
      f16x8 av[4], bv[4];
#pragma unroll
      for (int i = 0; i < 4; ++i) av[i] = *(const f16x8*)(base + ao[h][i]);
#pragma unroll
      for (int j = 0; j < 4; ++j) bv[j] = *(const f16x8*)(base + bo[h][j]);
#pragma unroll
      for (int i = 0; i < 4; ++i)
#pragma unroll
        for (int j = 0; j < 4; ++j)
          acc[i][j] = __builtin_amdgcn_mfma_f32_16x16x32_f16(av[i], bv[j], acc[i][j], 0, 0, 0);
    }
    cur ^= 1;
  }

  // epilogue: C row = (lane>>4)*4+reg, col = lane&15 (m89 layout)
#pragma unroll
  for (int i = 0; i < 4; ++i) {
#pragma unroll
    for (int j = 0; j < 4; ++j) {
      int mb = bm0 + wm * 64 + i * 16 + ((lane >> 4) << 2);
      int n = bn0 + wn * 64 + j * 16 + (lane & 15);
      if constexpr (EPI == 1) {  // proj split into q*SCALE | k | vT
        int b = mb >> 11, l0 = mb & 2047;
        if (n < EDIM) {
          u16* dst = p.qk + (long)b * 4194304 + (long)l0 * 1024 + n;
#pragma unroll
          for (int r = 0; r < 4; ++r) dst[r * 1024] = f2h(acc[i][j][r] * p.scale);
        } else if (n < 2 * EDIM) {
          u16* dst = p.qk + (long)b * 4194304 + 2097152 + (long)l0 * 1024 + (n - EDIM);
#pragma unroll
          for (int r = 0; r < 4; ++r) dst[r * 1024] = f2h(acc[i][j][r]);
        } else {  // vT[b][n-2048][l0..l0+3] -- 8B packed store
          u16* dst = p.vT + (long)b * 1048576 + (long)(n - 2 * EDIM) * 2048 + l0;
          u32x2 w = {pk(acc[i][j][0], acc[i][j][1]), pk(acc[i][j][2], acc[i][j][3])};
          *(u32x2*)dst = w;
        }
      } else if constexpr (EPI == 3) {  // +bias +resid, f16 out (ff2), ld 512
        float bias = p.bias[n];
        u16* dst = p.Cb + (long)mb * 512 + n;
        const u16* rs = p.resid + (long)mb * 512 + n;
#pragma unroll
        for (int r = 0; r < 4; ++r) dst[r * 512] = f2h(acc[i][j][r] + bias + h2f(rs[r * 512]));
      } else {  // EPI 4: plain f16 (PV)
        u16* dst = p.Cb + (long)z * p.bsC + (long)mb * p.ldc + n;
#pragma unroll
        for (int r = 0; r < 4; ++r) dst[(long)r * p.ldc] = f2h(acc[i][j][r]);
      }
    }
  }
}

// =======================================================================
// 256x256 tile, BK=64, 8 waves, covered 2-phase + XCD remap (scores, ff1).
// =======================================================================
template <int EPI>
__global__ __launch_bounds__(512, 2) void gemm256(GemmP p) {
  __shared__ __align__(16) char lds[131072];
  const int tid = threadIdx.x;
  const int lane = tid & 63;
  const int wave = tid >> 6;
  const int wm = wave >> 2, wn = wave & 3;   // 2 x 4 waves
  int bxi, byi, bzi;
  xcd_remap(bxi, byi, bzi);
  const int bn0 = bxi * 256;
  const int bm0 = byi * 256;
  const int z = bzi;

  const u16* gA[4]; const u16* gB[4];
  int ldsA[4], ldsB[4];
  {
    const u16* Ab = p.A + (long)z * p.bsA + (long)bm0 * p.lda;
    const u16* Bb = p.B + (long)z * p.bsB + (long)bn0 * p.ldb;
#pragma unroll
    for (int i = 0; i < 4; ++i) {
      int ch = i * 512 + tid;
      int row = ch >> 3, s = ch & 7;
      int ks = ((s ^ (row & 7)) << 3);
      gA[i] = Ab + (long)row * p.lda + ks;
      gB[i] = Bb + (long)row * p.ldb + ks;
      ldsA[i] = ch * 16;
      ldsB[i] = 32768 + ch * 16;
    }
  }
  auto stage = [&](int buf) {
    char* dst = lds + buf * 65536;
#pragma unroll
    for (int i = 0; i < 4; ++i) {
      __builtin_amdgcn_global_load_lds(
          (const __attribute__((address_space(1))) u32*)gA[i],
          (__attribute__((address_space(3))) u32*)(dst + ldsA[i]), 16, 0, 0);
      gA[i] += 64;
    }
#pragma unroll
    for (int i = 0; i < 4; ++i) {
      __builtin_amdgcn_global_load_lds(
          (const __attribute__((address_space(1))) u32*)gB[i],
          (__attribute__((address_space(3))) u32*)(dst + ldsB[i]), 16, 0, 0);
      gB[i] += 64;
    }
  };

  int abase[2], bbase[2];
  {
    int rA = wm * 128 + (lane & 15);
    int sA = (lane >> 4) ^ (lane & 7);
    abase[0] = rA * 128 + (sA << 4);
    abase[1] = abase[0] ^ 64;
    int rB = wn * 64 + (lane & 15);
    int sB = (lane >> 4) ^ (lane & 7);
    bbase[0] = 32768 + rB * 128 + (sB << 4);
    bbase[1] = bbase[0] ^ 64;
  }

  f32x4 acc[8][4] = {};
  stage(0);
  const int nk = p.K >> 6;
  int cur = 0;
  for (int kt = 0; kt < nk; ++kt) {
    __syncthreads();
    if (kt + 1 < nk) stage(cur ^ 1);
    const char* base = lds + cur * 65536;
#pragma unroll
    for (int h = 0; h < 2; ++h) {
      f16x8 av[8], bv[4];
#pragma unroll
      for (int m = 0; m < 8; ++m) av[m] = *(const f16x8*)(base + abase[h] + m * 2048);
#pragma unroll
      for (int j = 0; j < 4; ++j) bv[j] = *(const f16x8*)(base + bbase[h] + j * 2048);
#pragma unroll
      for (int m = 0; m < 8; ++m)
#pragma unroll
        for (int j = 0; j < 4; ++j)
          acc[m][j] = __builtin_amdgcn_mfma_f32_16x16x32_f16(av[m], bv[j], acc[m][j], 0, 0, 0);
    }
    cur ^= 1;
  }

#pragma unroll
  for (int i = 0; i < 8; ++i) {
#pragma unroll
    for (int j = 0; j < 4; ++j) {
      int mb = bm0 + wm * 128 + i * 16 + ((lane >> 4) << 2);
      int n = bn0 + wn * 64 + j * 16 + (lane & 15);
      if constexpr (EPI == 2) {  // +bias, relu, f16 out (ff1)
        u16* dst = p.Cb + (long)mb * p.ldc + n;
        float bias = p.bias[n];
#pragma unroll
        for (int r = 0; r < 4; ++r) dst[(long)r * p.ldc] = f2h(fmaxf(acc[i][j][r] + bias, 0.f));
      } else {  // EPI 4: plain f16 (scores)
        u16* dst = p.Cb + (long)z * p.bsC + (long)mb * p.ldc + n;
#pragma unroll
        for (int r = 0; r < 4; ++r) dst[(long)r * p.ldc] = f2h(acc[i][j][r]);
      }
    }
  }
}

// ---------- row softmax: 1 WAVE / row, chunk-interleaved coalesced ----------
__global__ __launch_bounds__(256) void softmax_rows(const u16* __restrict__ S,
                                                    u16* __restrict__ W, int b0) {
  int row = blockIdx.x * 4 + (threadIdx.x >> 6);
  int lane = threadIdx.x & 63;
  int z = row >> 11, l = row & 2047;
  const u16* x = S + (long)row * 2048;
  u32x4 raw[4];
#pragma unroll
  for (int c = 0; c < 4; ++c) raw[c] = *(const u32x4*)(x + c * 512 + lane * 8);
  float e[32];
#pragma unroll
  for (int c = 0; c < 4; ++c)
#pragma unroll
    for (int q = 0; q < 4; ++q) {
      e[c * 8 + 2 * q] = h2f((u16)(raw[c][q] & 0xffff));
      e[c * 8 + 2 * q + 1] = h2f((u16)(raw[c][q] >> 16));
    }
  float m = e[0];
#pragma unroll
  for (int q = 1; q < 32; ++q) m = fmaxf(m, e[q]);
#pragma unroll
  for (int off = 32; off; off >>= 1) m = fmaxf(m, __shfl_xor(m, off));
  float s = 0.f;
#pragma unroll
  for (int q = 0; q < 32; ++q) { e[q] = __expf(e[q] - m); s += e[q]; }
#pragma unroll
  for (int off = 32; off; off >>= 1) s += __shfl_xor(s, off);
  float inv = 1.f / s;
  u16* dst = W + (long)(b0 + z) * 4194304 + (long)l * 2048;
#pragma unroll
  for (int c = 0; c < 4; ++c) {
    u32x4 o = {pk(e[c * 8 + 0] * inv, e[c * 8 + 1] * inv),
               pk(e[c * 8 + 2] * inv, e[c * 8 + 3] * inv),
               pk(e[c * 8 + 4] * inv, e[c * 8 + 5] * inv),
               pk(e[c * 8 + 6] * inv, e[c * 8 + 7] * inv)};
    *(u32x4*)(dst + c * 512 + lane * 8) = o;
  }
}

// ---------- LayerNorm over 512, wave per row ----------
template <int INF16, int OUTF16>
__global__ __launch_bounds__(256) void ln_rows(const void* __restrict__ X,
                                               const float* __restrict__ g,
                                               const float* __restrict__ bb,
                                               void* __restrict__ out) {
  int row = blockIdx.x * 4 + (threadIdx.x >> 6);
  int lane = threadIdx.x & 63;
  float v[8];
  if constexpr (INF16) {
    u32x4 raw = *(const u32x4*)((const u16*)X + (long)row * 512 + lane * 8);
#pragma unroll
    for (int q = 0; q < 4; ++q) {
      v[2 * q] = h2f((u16)(raw[q] & 0xffff));
      v[2 * q + 1] = h2f((u16)(raw[q] >> 16));
    }
  } else {
    const float* x = (const float*)X + (long)row * 512 + lane * 8;
    f32x4 a = *(const f32x4*)x, b = *(const f32x4*)(x + 4);
#pragma unroll
    for (int q = 0; q < 4; ++q) { v[q] = a[q]; v[4 + q] = b[q]; }
  }
  float s = 0.f, sq = 0.f;
#pragma unroll
  for (int q = 0; q < 8; ++q) { s += v[q]; sq += v[q] * v[q]; }
#pragma unroll
  for (int off = 32; off; off >>= 1) {
    s += __shfl_xor(s, off);
    sq += __shfl_xor(sq, off);
  }
  float mean = s * (1.f / 512.f);
  float var = sq * (1.f / 512.f) - mean * mean;
  float rstd = rsqrtf(var + 1e-5f);
  f32x4 g0 = *(const f32x4*)(g + lane * 8), g1v = *(const f32x4*)(g + lane * 8 + 4);
  f32x4 b0 = *(const f32x4*)(bb + lane * 8), b1v = *(const f32x4*)(bb + lane * 8 + 4);
  float o[8];
#pragma unroll
  for (int q = 0; q < 4; ++q) o[q] = (v[q] - mean) * rstd * g0[q] + b0[q];
#pragma unroll
  for (int q = 0; q < 4; ++q) o[4 + q] = (v[4 + q] - mean) * rstd * g1v[q] + b1v[q];
  if constexpr (OUTF16) {
    u32x4 pkd = {pk(o[0], o[1]), pk(o[2], o[3]), pk(o[4], o[5]), pk(o[6], o[7])};
    *(u32x4*)((u16*)out + (long)row * 512 + lane * 8) = pkd;
  } else {
    float* dst = (float*)out + (long)row * 512 + lane * 8;
    *(f32x4*)dst = (f32x4){o[0], o[1], o[2], o[3]};
    *(f32x4*)(dst + 4) = (f32x4){o[4], o[5], o[6], o[7]};
  }
}

// ---------- launch ----------
extern "C" void kernel_launch(void* const* d_in, const int* in_sizes, int n_in,
                              void* d_out, int out_size, void* d_ws, size_t ws_size,
                              hipStream_t stream) {
  const float* x = (const float*)d_in[0];
  const float* wp = (const float*)d_in[1];
  const float* w1 = (const float*)d_in[2];
  const float* b1 = (const float*)d_in[3];
  const float* w2 = (const float*)d_in[4];
  const float* b2 = (const float*)d_in[5];
  const float* g1 = (const float*)d_in[6];
  const float* be1 = (const float*)d_in[7];
  const float* g2 = (const float*)d_in[8];
  const float* be2 = (const float*)d_in[9];

  char* ws = (char*)d_ws;
  size_t off = 0;
  auto alloc = [&](size_t bytes) {
    char* p = ws + off;
    off += (bytes + 255) & ~(size_t)255;
    return p;
  };
  u16* wpb = (u16*)alloc(2560 * 1024 * 2);
  u16* w1b = (u16*)alloc(2048 * 512 * 2);
  u16* w2b = (u16*)alloc(512 * 2048 * 2);
  char* xb_region = alloc(33554432);            // x f16 -> attn_out f16
  u16* qk = (u16*)alloc(67108864);              // [q|k] f16 -> attnw -> ff1
  u16* vT = (u16*)alloc(16777216);              // v transposed f16
  u16* hb = (u16*)alloc(16777216);              // h f16
  int bpl = (ws_size >= off + (size_t)67108864) ? 8 : 4;
  char* sc_region = alloc((size_t)bpl * 2048 * 2048 * 2);
  if (off > ws_size) return;

  u16* xb = (u16*)xb_region;
  u16* attn16 = (u16*)xb_region;
  u16* scores = (u16*)sc_region;
  u16* y16 = (u16*)sc_region;
  u16* ff1 = qk;

  const float SC = (float)(0.03125 * 2.0 * 7.6246189861593985);

  cvt_all<<<dim3(10496), dim3(256), 0, stream>>>(x, xb, wp, wpb, w1, w1b, w2, w2b);

  {  // proj: (16384x1024) @ (2560x1024)^T  [128^2 BK=64 covered + T1]
    GemmP p{};
    p.A = xb; p.lda = 1024; p.B = wpb; p.ldb = 1024; p.K = 1024;
    p.qk = qk; p.vT = vT; p.scale = SC;
    gemm_bt<1><<<dim3(20, 128, 1), 256, 0, stream>>>(p);
  }

  for (int it = 0; it < 8 / bpl; ++it) {  // scores + softmax  [256^2 + T1]
    int b0 = it * bpl;
    GemmP p{};
    p.A = qk + (long)b0 * 4194304; p.lda = 1024; p.bsA = 4194304;
    p.B = qk + (long)b0 * 4194304 + 2097152; p.ldb = 1024; p.bsB = 4194304;
    p.K = 1024; p.Cb = scores; p.ldc = 2048; p.bsC = 4194304;
    gemm256<4><<<dim3(8, 8, bpl), 512, 0, stream>>>(p);
    softmax_rows<<<dim3(bpl * 512), dim3(256), 0, stream>>>(scores, qk, b0);
  }

  {  // PV: attnw(2048x2048) @ vT(512x2048)^T -> f16  [128^2 covered + T1]
    GemmP p{};
    p.A = qk; p.lda = 2048; p.bsA = 4194304;
    p.B = vT; p.ldb = 2048; p.bsB = 1048576;
    p.K = 2048; p.Cb = attn16; p.ldc = 512; p.bsC = 1048576;
    gemm_bt<4><<<dim3(4, 16, 8), 256, 0, stream>>>(p);
  }

  ln_rows<1, 1><<<dim3(4096), dim3(256), 0, stream>>>(attn16, g1, be1, hb);

  {  // ff1: h(16384x512) @ w1(2048x512)^T, +b1 relu -> f16  [256^2 + T1]
    GemmP p{};
    p.A = hb; p.lda = 512; p.B = w1b; p.ldb = 512; p.K = 512;
    p.Cb = ff1; p.ldc = 2048; p.bias = b1;
    gemm256<2><<<dim3(8, 64, 1), 512, 0, stream>>>(p);
  }

  {  // ff2: ff1(16384x2048) @ w2(512x2048)^T, +b2 +h -> f16  [128^2 + T1]
    GemmP p{};
    p.A = ff1; p.lda = 2048; p.B = w2b; p.ldb = 2048; p.K = 2048;
    p.Cb = y16; p.bias = b2; p.resid = hb;
    gemm_bt<3><<<dim3(4, 128, 1), 256, 0, stream>>>(p);
  }

  ln_rows<1, 0><<<dim3(4096), dim3(256), 0, stream>>>(y16, g2, be2, (float*)d_out);
}

// Round 14
// 347.473 us; speedup vs baseline: 1.1118x; 1.0118x over previous
//
#include <hip/hip_runtime.h>
#include <hip/hip_bf16.h>

// ---------- types ----------
typedef unsigned short u16;
typedef unsigned int u32;
typedef float f32x4 __attribute__((ext_vector_type(4)));
typedef _Float16 f16x8 __attribute__((ext_vector_type(8)));
typedef u32 u32x4 __attribute__((ext_vector_type(4)));
typedef u32 u32x2 __attribute__((ext_vector_type(2)));

#define SEQ 2048
#define EDIM 1024

__device__ __forceinline__ u16 f2h(float f) {
  _Float16 h = (_Float16)f;
  return __builtin_bit_cast(u16, h);
}
__device__ __forceinline__ float h2f(u16 u) {
  return (float)__builtin_bit_cast(_Float16, u);
}
__device__ __forceinline__ u32 pk(float a, float b) {
  return (u32)f2h(a) | ((u32)f2h(b) << 16);
}

// XCD-aware bijective block remap (T1): blocks sharing an operand panel land
// on the SAME XCD's L2. Requires nwg % 8 == 0 (grids: 2560, 512, 512, 512, 512).
__device__ __forceinline__ void xcd_remap(int& bx, int& by, int& bz) {
  int gx = gridDim.x, gy = gridDim.y;
  int lin = (blockIdx.z * gy + blockIdx.y) * gx + blockIdx.x;
  int nwg = gx * gy * gridDim.z;
  int nl = (lin & 7) * (nwg >> 3) + (lin >> 3);
  bx = nl % gx;
  int t = nl / gx;
  by = t % gy;
  bz = t / gy;
}

// ---------- fused fp32 -> fp16 convert for all 4 inputs, 8 elems/thread ----
#define N_X  2097152
#define N_WP 327680
#define N_W1 131072
#define N_W2 131072
__global__ __launch_bounds__(256) void cvt_all(const float* __restrict__ x, u16* __restrict__ xb,
                                               const float* __restrict__ wp, u16* __restrict__ wpb,
                                               const float* __restrict__ w1, u16* __restrict__ w1b,
                                               const float* __restrict__ w2, u16* __restrict__ w2b) {
  int i = blockIdx.x * 256 + threadIdx.x;
  const float* src; u16* dst; int li;
  if (i < N_X) { src = x; dst = xb; li = i; }
  else if (i < N_X + N_WP) { src = wp; dst = wpb; li = i - N_X; }
  else if (i < N_X + N_WP + N_W1) { src = w1; dst = w1b; li = i - N_X - N_WP; }
  else if (i < N_X + N_WP + N_W1 + N_W2) { src = w2; dst = w2b; li = i - N_X - N_WP - N_W1; }
  else return;
  const f32x4* p = (const f32x4*)(src + (size_t)li * 8);
  f32x4 a = p[0], b = p[1];
  u32x4 o = {pk(a[0], a[1]), pk(a[2], a[3]), pk(b[0], b[1]), pk(b[2], b[3])};
  *(u32x4*)(dst + (size_t)li * 8) = o;
}

struct GemmP {
  const u16* A; const u16* B;
  int lda, ldb, K;
  long bsA, bsB, bsC;       // per-z element strides
  int ldc;
  int nPerZ;                // EPI 1: global N offset per z (proj N-split)
  u16* Cb;                  // f16 store
  const float* bias;        // EPI 2,3
  const u16* resid;         // EPI 3 (h, f16, ld 512)
  u16* qk; u16* vT;         // EPI 1 (proj split)
  float scale;              // EPI 1
};

// =======================================================================
// 128x128 tile, BK=64, 4 waves (2x2), 16x16x32 f16 MFMA, COVERED-STAGING
// 2-phase double-buffer. LDS 64KB -> 2 blocks/CU. + XCD remap (T1).
// Used for proj (z = N-half so each XCD's B-half 2.5MB is L2-resident),
// PV, ff2.
// EPI: 1 = proj split (q*SC | k | vT), 3 = +bias +resid f16 (ff2),
//      4 = plain f16 (PV).
// =======================================================================
template <int EPI>
__global__ __launch_bounds__(256) void gemm_bt(GemmP p) {
  __shared__ __align__(16) char lds[65536];
  const int tid = threadIdx.x;
  const int lane = tid & 63;
  const int wave = tid >> 6;
  const int wm = wave >> 1, wn = wave & 1;
  int bxi, byi, bzi;
  xcd_remap(bxi, byi, bzi);
  const int bn0 = bxi * 128;
  const int bm0 = byi * 128;
  const int z = bzi;

  const u16* gA[4]; const u16* gB[4];
  int ldsA[4], ldsB[4];
  {
    const u16* Ab = p.A + (long)z * p.bsA + (long)bm0 * p.lda;
    const u16* Bb = p.B + (long)z * p.bsB + (long)bn0 * p.ldb;
#pragma unroll
    for (int i = 0; i < 4; ++i) {
      int ch = i * 256 + tid;
      int row = ch >> 3, s = ch & 7;
      int ks = ((s ^ (row & 7)) << 3);  // inverse-swizzled global source
      gA[i] = Ab + (long)row * p.lda + ks;
      gB[i] = Bb + (long)row * p.ldb + ks;
      ldsA[i] = ch * 16;
      ldsB[i] = 16384 + ch * 16;
    }
  }
  auto stage = [&](int buf) {
    char* dst = lds + buf * 32768;
#pragma unroll
    for (int i = 0; i < 4; ++i) {
      __builtin_amdgcn_global_load_lds(
          (const __attribute__((address_space(1))) u32*)gA[i],
          (__attribute__((address_space(3))) u32*)(dst + ldsA[i]), 16, 0, 0);
      gA[i] += 64;
    }
#pragma unroll
    for (int i = 0; i < 4; ++i) {
      __builtin_amdgcn_global_load_lds(
          (const __attribute__((address_space(1))) u32*)gB[i],
          (__attribute__((address_space(3))) u32*)(dst + ldsB[i]), 16, 0, 0);
      gB[i] += 64;
    }
  };

  int ao[2][4], bo[2][4];
#pragma unroll
  for (int h = 0; h < 2; ++h) {
#pragma unroll
    for (int i = 0; i < 4; ++i) {
      int rA = wm * 64 + i * 16 + (lane & 15);
      ao[h][i] = rA * 128 + ((((h << 2) | (lane >> 4)) ^ (rA & 7)) << 4);
      int rB = wn * 64 + i * 16 + (lane & 15);
      bo[h][i] = 16384 + rB * 128 + ((((h << 2) | (lane >> 4)) ^ (rB & 7)) << 4);
    }
  }

  f32x4 acc[4][4] = {};
  stage(0);
  const int nk = p.K >> 6;
  int cur = 0;
  for (int kt = 0; kt < nk; ++kt) {
    __syncthreads();                  // buf[cur] landed; drain covered by prev tile
    if (kt + 1 < nk) stage(cur ^ 1);  // issue next tile FIRST
    const char* base = lds + cur * 32768;
#pragma unroll
    for (int h = 0; h < 2; ++h) {
      f16x8 av[4], bv[4];
#pragma unroll
      for (int i = 0; i < 4; ++i) av[i] = *(const f16x8*)(base + ao[h][i]);
#pragma unroll
      for (int j = 0; j < 4; ++j) bv[j] = *(const f16x8*)(base + bo[h][j]);
#pragma unroll
      for (int i = 0; i < 4; ++i)
#pragma unroll
        for (int j = 0; j < 4; ++j)
          acc[i][j] = __builtin_amdgcn_mfma_f32_16x16x32_f16(av[i], bv[j], acc[i][j], 0, 0, 0);
    }
    cur ^= 1;
  }

  // epilogue: C row = (lane>>4)*4+reg, col = lane&15 (m89 layout)
#pragma unroll
  for (int i = 0; i < 4; ++i) {
#pragma unroll
    for (int j = 0; j < 4; ++j) {
      int mb = bm0 + wm * 64 + i * 16 + ((lane >> 4) << 2);
      int n = bn0 + wn * 64 + j * 16 + (lane & 15);
      if constexpr (EPI == 1) {  // proj split into q*SCALE | k | vT
        int ng = n + z * p.nPerZ;   // global column (N-split over z)
        int b = mb >> 11, l0 = mb & 2047;
        if (ng < EDIM) {
          u16* dst = p.qk + (long)b * 4194304 + (long)l0 * 1024 + ng;
#pragma unroll
          for (int r = 0; r < 4; ++r) dst[r * 1024] = f2h(acc[i][j][r] * p.scale);
        } else if (ng < 2 * EDIM) {
          u16* dst = p.qk + (long)b * 4194304 + 2097152 + (long)l0 * 1024 + (ng - EDIM);
#pragma unroll
          for (int r = 0; r < 4; ++r) dst[r * 1024] = f2h(acc[i][j][r]);
        } else {  // vT[b][ng-2048][l0..l0+3] -- 8B packed store
          u16* dst = p.vT + (long)b * 1048576 + (long)(ng - 2 * EDIM) * 2048 + l0;
          u32x2 w = {pk(acc[i][j][0], acc[i][j][1]), pk(acc[i][j][2], acc[i][j][3])};
          *(u32x2*)dst = w;
        }
      } else if constexpr (EPI == 3) {  // +bias +resid, f16 out (ff2), ld 512
        float bias = p.bias[n];
        u16* dst = p.Cb + (long)mb * 512 + n;
        const u16* rs = p.resid + (long)mb * 512 + n;
#pragma unroll
        for (int r = 0; r < 4; ++r) dst[r * 512] = f2h(acc[i][j][r] + bias + h2f(rs[r * 512]));
      } else {  // EPI 4: plain f16 (PV)
        u16* dst = p.Cb + (long)z * p.bsC + (long)mb * p.ldc + n;
#pragma unroll
        for (int r = 0; r < 4; ++r) dst[(long)r * p.ldc] = f2h(acc[i][j][r]);
      }
    }
  }
}

// =======================================================================
// 256x256 tile, BK=64, 8 waves, covered 2-phase + XCD remap (scores, ff1).
// =======================================================================
template <int EPI>
__global__ __launch_bounds__(512, 2) void gemm256(GemmP p) {
  __shared__ __align__(16) char lds[131072];
  const int tid = threadIdx.x;
  const int lane = tid & 63;
  const int wave = tid >> 6;
  const int wm = wave >> 2, wn = wave & 3;   // 2 x 4 waves
  int bxi, byi, bzi;
  xcd_remap(bxi, byi, bzi);
  const int bn0 = bxi * 256;
  const int bm0 = byi * 256;
  const int z = bzi;

  const u16* gA[4]; const u16* gB[4];
  int ldsA[4], ldsB[4];
  {
    const u16* Ab = p.A + (long)z * p.bsA + (long)bm0 * p.lda;
    const u16* Bb = p.B + (long)z * p.bsB + (long)bn0 * p.ldb;
#pragma unroll
    for (int i = 0; i < 4; ++i) {
      int ch = i * 512 + tid;
      int row = ch >> 3, s = ch & 7;
      int ks = ((s ^ (row & 7)) << 3);
      gA[i] = Ab + (long)row * p.lda + ks;
      gB[i] = Bb + (long)row * p.ldb + ks;
      ldsA[i] = ch * 16;
      ldsB[i] = 32768 + ch * 16;
    }
  }
  auto stage = [&](int buf) {
    char* dst = lds + buf * 65536;
#pragma unroll
    for (int i = 0; i < 4; ++i) {
      __builtin_amdgcn_global_load_lds(
          (const __attribute__((address_space(1))) u32*)gA[i],
          (__attribute__((address_space(3))) u32*)(dst + ldsA[i]), 16, 0, 0);
      gA[i] += 64;
    }
#pragma unroll
    for (int i = 0; i < 4; ++i) {
      __builtin_amdgcn_global_load_lds(
          (const __attribute__((address_space(1))) u32*)gB[i],
          (__attribute__((address_space(3))) u32*)(dst + ldsB[i]), 16, 0, 0);
      gB[i] += 64;
    }
  };

  int abase[2], bbase[2];
  {
    int rA = wm * 128 + (lane & 15);
    int sA = (lane >> 4) ^ (lane & 7);
    abase[0] = rA * 128 + (sA << 4);
    abase[1] = abase[0] ^ 64;
    int rB = wn * 64 + (lane & 15);
    int sB = (lane >> 4) ^ (lane & 7);
    bbase[0] = 32768 + rB * 128 + (sB << 4);
    bbase[1] = bbase[0] ^ 64;
  }

  f32x4 acc[8][4] = {};
  stage(0);
  const int nk = p.K >> 6;
  int cur = 0;
  for (int kt = 0; kt < nk; ++kt) {
    __syncthreads();
    if (kt + 1 < nk) stage(cur ^ 1);
    const char* base = lds + cur * 65536;
#pragma unroll
    for (int h = 0; h < 2; ++h) {
      f16x8 av[8], bv[4];
#pragma unroll
      for (int m = 0; m < 8; ++m) av[m] = *(const f16x8*)(base + abase[h] + m * 2048);
#pragma unroll
      for (int j = 0; j < 4; ++j) bv[j] = *(const f16x8*)(base + bbase[h] + j * 2048);
#pragma unroll
      for (int m = 0; m < 8; ++m)
#pragma unroll
        for (int j = 0; j < 4; ++j)
          acc[m][j] = __builtin_amdgcn_mfma_f32_16x16x32_f16(av[m], bv[j], acc[m][j], 0, 0, 0);
    }
    cur ^= 1;
  }

#pragma unroll
  for (int i = 0; i < 8; ++i) {
#pragma unroll
    for (int j = 0; j < 4; ++j) {
      int mb = bm0 + wm * 128 + i * 16 + ((lane >> 4) << 2);
      int n = bn0 + wn * 64 + j * 16 + (lane & 15);
      if constexpr (EPI == 2) {  // +bias, relu, f16 out (ff1)
        u16* dst = p.Cb + (long)mb * p.ldc + n;
        float bias = p.bias[n];
#pragma unroll
        for (int r = 0; r < 4; ++r) dst[(long)r * p.ldc] = f2h(fmaxf(acc[i][j][r] + bias, 0.f));
      } else {  // EPI 4: plain f16 (scores)
        u16* dst = p.Cb + (long)z * p.bsC + (long)mb * p.ldc + n;
#pragma unroll
        for (int r = 0; r < 4; ++r) dst[(long)r * p.ldc] = f2h(acc[i][j][r]);
      }
    }
  }
}

// ---------- row softmax: 1 WAVE / row, chunk-interleaved coalesced ----------
__global__ __launch_bounds__(256) void softmax_rows(const u16* __restrict__ S,
                                                    u16* __restrict__ W, int b0) {
  int row = blockIdx.x * 4 + (threadIdx.x >> 6);
  int lane = threadIdx.x & 63;
  int z = row >> 11, l = row & 2047;
  const u16* x = S + (long)row * 2048;
  u32x4 raw[4];
#pragma unroll
  for (int c = 0; c < 4; ++c) raw[c] = *(const u32x4*)(x + c * 512 + lane * 8);
  float e[32];
#pragma unroll
  for (int c = 0; c < 4; ++c)
#pragma unroll
    for (int q = 0; q < 4; ++q) {
      e[c * 8 + 2 * q] = h2f((u16)(raw[c][q] & 0xffff));
      e[c * 8 + 2 * q + 1] = h2f((u16)(raw[c][q] >> 16));
    }
  float m = e[0];
#pragma unroll
  for (int q = 1; q < 32; ++q) m = fmaxf(m, e[q]);
#pragma unroll
  for (int off = 32; off; off >>= 1) m = fmaxf(m, __shfl_xor(m, off));
  float s = 0.f;
#pragma unroll
  for (int q = 0; q < 32; ++q) { e[q] = __expf(e[q] - m); s += e[q]; }
#pragma unroll
  for (int off = 32; off; off >>= 1) s += __shfl_xor(s, off);
  float inv = 1.f / s;
  u16* dst = W + (long)(b0 + z) * 4194304 + (long)l * 2048;
#pragma unroll
  for (int c = 0; c < 4; ++c) {
    u32x4 o = {pk(e[c * 8 + 0] * inv, e[c * 8 + 1] * inv),
               pk(e[c * 8 + 2] * inv, e[c * 8 + 3] * inv),
               pk(e[c * 8 + 4] * inv, e[c * 8 + 5] * inv),
               pk(e[c * 8 + 6] * inv, e[c * 8 + 7] * inv)};
    *(u32x4*)(dst + c * 512 + lane * 8) = o;
  }
}

// ---------- LayerNorm over 512, wave per row ----------
template <int INF16, int OUTF16>
__global__ __launch_bounds__(256) void ln_rows(const void* __restrict__ X,
                                               const float* __restrict__ g,
                                               const float* __restrict__ bb,
                                               void* __restrict__ out) {
  int row = blockIdx.x * 4 + (threadIdx.x >> 6);
  int lane = threadIdx.x & 63;
  float v[8];
  if constexpr (INF16) {
    u32x4 raw = *(const u32x4*)((const u16*)X + (long)row * 512 + lane * 8);
#pragma unroll
    for (int q = 0; q < 4; ++q) {
      v[2 * q] = h2f((u16)(raw[q] & 0xffff));
      v[2 * q + 1] = h2f((u16)(raw[q] >> 16));
    }
  } else {
    const float* x = (const float*)X + (long)row * 512 + lane * 8;
    f32x4 a = *(const f32x4*)x, b = *(const f32x4*)(x + 4);
#pragma unroll
    for (int q = 0; q < 4; ++q) { v[q] = a[q]; v[4 + q] = b[q]; }
  }
  float s = 0.f, sq = 0.f;
#pragma unroll
  for (int q = 0; q < 8; ++q) { s += v[q]; sq += v[q] * v[q]; }
#pragma unroll
  for (int off = 32; off; off >>= 1) {
    s += __shfl_xor(s, off);
    sq += __shfl_xor(sq, off);
  }
  float mean = s * (1.f / 512.f);
  float var = sq * (1.f / 512.f) - mean * mean;
  float rstd = rsqrtf(var + 1e-5f);
  f32x4 g0 = *(const f32x4*)(g + lane * 8), g1v = *(const f32x4*)(g + lane * 8 + 4);
  f32x4 b0 = *(const f32x4*)(bb + lane * 8), b1v = *(const f32x4*)(bb + lane * 8 + 4);
  float o[8];
#pragma unroll
  for (int q = 0; q < 4; ++q) o[q] = (v[q] - mean) * rstd * g0[q] + b0[q];
#pragma unroll
  for (int q = 0; q < 4; ++q) o[4 + q] = (v[4 + q] - mean) * rstd * g1v[q] + b1v[q];
  if constexpr (OUTF16) {
    u32x4 pkd = {pk(o[0], o[1]), pk(o[2], o[3]), pk(o[4], o[5]), pk(o[6], o[7])};
    *(u32x4*)((u16*)out + (long)row * 512 + lane * 8) = pkd;
  } else {
    float* dst = (float*)out + (long)row * 512 + lane * 8;
    *(f32x4*)dst = (f32x4){o[0], o[1], o[2], o[3]};
    *(f32x4*)(dst + 4) = (f32x4){o[4], o[5], o[6], o[7]};
  }
}

// ---------- launch ----------
extern "C" void kernel_launch(void* const* d_in, const int* in_sizes, int n_in,
                              void* d_out, int out_size, void* d_ws, size_t ws_size,
                              hipStream_t stream) {
  const float* x = (const float*)d_in[0];
  const float* wp = (const float*)d_in[1];
  const float* w1 = (const float*)d_in[2];
  const float* b1 = (const float*)d_in[3];
  const float* w2 = (const float*)d_in[4];
  const float* b2 = (const float*)d_in[5];
  const float* g1 = (const float*)d_in[6];
  const float* be1 = (const float*)d_in[7];
  const float* g2 = (const float*)d_in[8];
  const float* be2 = (const float*)d_in[9];

  char* ws = (char*)d_ws;
  size_t off = 0;
  auto alloc = [&](size_t bytes) {
    char* p = ws + off;
    off += (bytes + 255) & ~(size_t)255;
    return p;
  };
  u16* wpb = (u16*)alloc(2560 * 1024 * 2);
  u16* w1b = (u16*)alloc(2048 * 512 * 2);
  u16* w2b = (u16*)alloc(512 * 2048 * 2);
  char* xb_region = alloc(33554432);            // x f16 -> attn_out f16
  u16* qk = (u16*)alloc(67108864);              // [q|k] f16 -> attnw -> ff1
  u16* vT = (u16*)alloc(16777216);              // v transposed f16
  u16* hb = (u16*)alloc(16777216);              // h f16
  int bpl = (ws_size >= off + (size_t)67108864) ? 8 : 4;
  char* sc_region = alloc((size_t)bpl * 2048 * 2048 * 2);
  if (off > ws_size) return;

  u16* xb = (u16*)xb_region;
  u16* attn16 = (u16*)xb_region;
  u16* scores = (u16*)sc_region;
  u16* y16 = (u16*)sc_region;
  u16* ff1 = qk;

  const float SC = (float)(0.03125 * 2.0 * 7.6246189861593985);

  cvt_all<<<dim3(10496), dim3(256), 0, stream>>>(x, xb, wp, wpb, w1, w1b, w2, w2b);

  {  // proj: (16384x1024) @ (2560x1024)^T  [128^2 covered + T1, N-split z=2:
     //  each XCD's 2.5MB B-half is L2-resident]
    GemmP p{};
    p.A = xb; p.lda = 1024; p.bsA = 0;
    p.B = wpb; p.ldb = 1024; p.bsB = 1280 * 1024; p.nPerZ = 1280;
    p.K = 1024;
    p.qk = qk; p.vT = vT; p.scale = SC;
    gemm_bt<1><<<dim3(10, 128, 2), 256, 0, stream>>>(p);
  }

  for (int it = 0; it < 8 / bpl; ++it) {  // scores + softmax  [256^2 + T1]
    int b0 = it * bpl;
    GemmP p{};
    p.A = qk + (long)b0 * 4194304; p.lda = 1024; p.bsA = 4194304;
    p.B = qk + (long)b0 * 4194304 + 2097152; p.ldb = 1024; p.bsB = 4194304;
    p.K = 1024; p.Cb = scores; p.ldc = 2048; p.bsC = 4194304;
    gemm256<4><<<dim3(8, 8, bpl), 512, 0, stream>>>(p);
    softmax_rows<<<dim3(bpl * 512), dim3(256), 0, stream>>>(scores, qk, b0);
  }

  {  // PV: attnw(2048x2048) @ vT(512x2048)^T -> f16  [128^2 covered + T1]
    GemmP p{};
    p.A = qk; p.lda = 2048; p.bsA = 4194304;
    p.B = vT; p.ldb = 2048; p.bsB = 1048576;
    p.K = 2048; p.Cb = attn16; p.ldc = 512; p.bsC = 1048576;
    gemm_bt<4><<<dim3(4, 16, 8), 256, 0, stream>>>(p);
  }

  ln_rows<1, 1><<<dim3(4096), dim3(256), 0, stream>>>(attn16, g1, be1, hb);

  {  // ff1: h(16384x512) @ w1(2048x512)^T, +b1 relu -> f16  [256^2 + T1]
    GemmP p{};
    p.A = hb; p.lda = 512; p.B = w1b; p.ldb = 512; p.K = 512;
    p.Cb = ff1; p.ldc = 2048; p.bias = b1;
    gemm256<2><<<dim3(8, 64, 1), 512, 0, stream>>>(p);
  }

  {  // ff2: ff1(16384x2048) @ w2(512x2048)^T, +b2 +h -> f16  [128^2 + T1]
    GemmP p{};
    p.A = ff1; p.lda = 2048; p.B = w2b; p.ldb = 2048; p.K = 2048;
    p.Cb = y16; p.bias = b2; p.resid = hb;
    gemm_bt<3><<<dim3(4, 128, 1), 256, 0, stream>>>(p);
  }

  ln_rows<1, 0><<<dim3(4096), dim3(256), 0, stream>>>(y16, g2, be2, (float*)d_out);
}